// Round 9
// baseline (34.272 us; speedup 1.0000x reference)
//
#include <hip/hip_runtime.h>

// TransformerBlockQuantum: B=16384, S=8, E=8, H=8 (dk=1), NW=8, FFN=512.
// R9 = R8 with ds_swizzle literal-pattern fix (hand-unrolled 8-group gathers).
// 8 lanes per token: lane = s*8 + e. Wave = 8 tokens = one batch -> attention
// wave-local. e-type gathers via ds_swizzle 8-group bcast (literal patterns);
// seq-type attention gather via wave-wide ds_bpermute; LN via xor butterflies.
// Block = 128 thr = 2 waves = 16 tokens = one 16x16 MFMA FFN tile, split-K
// across waves with prepacked half4 fragments from d_ws; wave0 LN2+store.
// 8192 blocks -> 16384 waves.

typedef __fp16 half2v __attribute__((ext_vector_type(2)));
typedef __fp16 half4  __attribute__((ext_vector_type(4)));
typedef float  float4v __attribute__((ext_vector_type(4)));

#define SWZ8_(v, dlit) __int_as_float(__builtin_amdgcn_ds_swizzle(__float_as_int(v), (dlit << 5) | 0x18))
// gather all 8 members of own 8-group into dst[0..7]
#define GATHER8(dst, v)                         \
    do {                                        \
        dst[0] = SWZ8_(v, 0); dst[1] = SWZ8_(v, 1); \
        dst[2] = SWZ8_(v, 2); dst[3] = SWZ8_(v, 3); \
        dst[4] = SWZ8_(v, 4); dst[5] = SWZ8_(v, 5); \
        dst[6] = SWZ8_(v, 6); dst[7] = SWZ8_(v, 7); \
    } while (0)
// butterfly: partner = id5 ^ m (literal m)
#define SWZX(v, m) __int_as_float(__builtin_amdgcn_ds_swizzle(__float_as_int(v), ((m) << 10) | 0x1F))
#define BPERM(idx, v) __int_as_float(__builtin_amdgcn_ds_bpermute((idx), __float_as_int(v)))

__global__ __launch_bounds__(256) void pack_frags(
    const float* __restrict__ l1w, const float* __restrict__ l1b,
    const float* __restrict__ l2w,
    half4* __restrict__ a1ws, half4* __restrict__ a2ws)
{
    int t = blockIdx.x * 256 + threadIdx.x;   // 0..4095
    int u = t & 2047;
    int nf = u >> 6, l = u & 63;
    int m = l & 15, k0 = (l >> 4) * 4;
    half4 r;
    if (t < 2048) {
        int f = nf * 16 + m;
        #pragma unroll
        for (int j = 0; j < 4; ++j) {
            int k = k0 + j;
            float v = (k < 8) ? l1w[f * 8 + k] : ((k == 8) ? l1b[f] : 0.f);
            r[j] = (__fp16)v;
        }
        a1ws[nf * 64 + l] = r;
    } else {
        #pragma unroll
        for (int j = 0; j < 4; ++j) {
            int k = k0 + j;
            float v = (m < 8) ? l2w[m * 512 + nf * 16 + k] : 0.f;
            r[j] = (__fp16)v;
        }
        a2ws[nf * 64 + l] = r;
    }
}

__global__ __launch_bounds__(128) void tbq_fused(
    const float* __restrict__ x,
    const float* __restrict__ ipw, const float* __restrict__ ipb,
    const float* __restrict__ opw, const float* __restrict__ opb,
    const float* __restrict__ rxa,
    const float* __restrict__ cw,  const float* __restrict__ cb,
    const float* __restrict__ g1,  const float* __restrict__ b1,
    const float* __restrict__ rxf,
    const half4* __restrict__ a1ws, const half4* __restrict__ a2ws,
    const float* __restrict__ l2b,
    const float* __restrict__ g2,  const float* __restrict__ b2,
    float* __restrict__ out)
{
    __shared__ __align__(16) float lds_zf[16][12];   // stride 12: aligned f4 reads
    __shared__ __align__(16) float lds_hh[16][12];
    __shared__ __align__(16) float lds_acc[32][4];

    const int tid = threadIdx.x;
    const int l   = tid & 63;
    const int wv  = tid >> 6;
    const int e   = l & 7;        // embed / head / wire role
    const int s   = l >> 3;       // seq pos within this wave's batch
    const int tblk = wv * 8 + s;  // block-local token (0..15)

    // own x element: idx = blk*128 + wv*64 + l
    const float xo = x[blockIdx.x * 128 + wv * 64 + l];

    // ---- gather x row of own token ----
    float xd[8];
    GATHER8(xd, xo);

    // ---- in_proj rows e, 8+e, 16+e (vector loads, L1-hot) ----
    const float4* ipw4 = reinterpret_cast<const float4*>(ipw);
    float4 wq0 = ipw4[e * 2],      wq1 = ipw4[e * 2 + 1];
    float4 wk0 = ipw4[16 + e * 2], wk1 = ipw4[16 + e * 2 + 1];
    float4 wv0 = ipw4[32 + e * 2], wv1 = ipw4[32 + e * 2 + 1];
    float qv = ipb[e]      + xd[0]*wq0.x + xd[1]*wq0.y + xd[2]*wq0.z + xd[3]*wq0.w
                           + xd[4]*wq1.x + xd[5]*wq1.y + xd[6]*wq1.z + xd[7]*wq1.w;
    float kv = ipb[8 + e]  + xd[0]*wk0.x + xd[1]*wk0.y + xd[2]*wk0.z + xd[3]*wk0.w
                           + xd[4]*wk1.x + xd[5]*wk1.y + xd[6]*wk1.z + xd[7]*wk1.w;
    float vv_ = ipb[16 + e]+ xd[0]*wv0.x + xd[1]*wv0.y + xd[2]*wv0.z + xd[3]*wv0.w
                           + xd[4]*wv1.x + xd[5]*wv1.y + xd[6]*wv1.z + xd[7]*wv1.w;

    // ---- attention head h=e, query s: gather k[h](j), v[h](j) wave-wide ----
    const int pbase = e * 4;               // byte index of lane (j=0, h=e)
    float kk[8], vg[8];
    #pragma unroll
    for (int j = 0; j < 8; ++j) {
        kk[j] = BPERM(pbase + j * 32, kv);
        vg[j] = BPERM(pbase + j * 32, vv_);
    }
    float sc[8];
    #pragma unroll
    for (int j = 0; j < 8; ++j) sc[j] = qv * kk[j];
    float mx = fmaxf(fmaxf(fmaxf(sc[0], sc[1]), fmaxf(sc[2], sc[3])),
                     fmaxf(fmaxf(sc[4], sc[5]), fmaxf(sc[6], sc[7])));
    float p[8];
    #pragma unroll
    for (int j = 0; j < 8; ++j) p[j] = __expf(sc[j] - mx);
    float psum = ((p[0] + p[1]) + (p[2] + p[3])) + ((p[4] + p[5]) + (p[6] + p[7]));
    float ov = 0.f;
    #pragma unroll
    for (int j = 0; j < 8; ++j) ov = fmaf(p[j], vg[j], ov);
    const float orw = ov * __builtin_amdgcn_rcpf(psum);   // orow[s][h=e]

    // ---- out_proj row e ----
    float og[8];
    GATHER8(og, orw);
    const float4* opw4 = reinterpret_cast<const float4*>(opw);
    float4 wo0 = opw4[e * 2], wo1 = opw4[e * 2 + 1];
    float ao = opb[e] + og[0]*wo0.x + og[1]*wo0.y + og[2]*wo0.z + og[3]*wo0.w
                      + og[4]*wo1.x + og[5]*wo1.y + og[6]*wo1.z + og[7]*wo1.w;

    // ---- quantum ring: c = cos(ao + rxa), CNOT-ring Z for wire w=e ----
    float cv = __cosf(ao + rxa[e]);
    float cg[8];
    GATHER8(cg, cv);
    float run = cg[0];
    float zv = 0.f;
    #pragma unroll
    for (int j = 1; j < 8; ++j) { run *= cg[j]; zv = (e == j) ? run : zv; }
    float s17 = cg[1];
    #pragma unroll
    for (int j = 2; j < 8; ++j) s17 *= cg[j];
    zv = (e == 0) ? s17 : zv;

    // ---- combine twice (row e of cw reused) ----
    const float4* cw4 = reinterpret_cast<const float4*>(cw);
    float4 wc0 = cw4[e * 2], wc1 = cw4[e * 2 + 1];
    float zg[8];
    GATHER8(zg, zv);
    float qo = cb[e] + zg[0]*wc0.x + zg[1]*wc0.y + zg[2]*wc0.z + zg[3]*wc0.w
                     + zg[4]*wc1.x + zg[5]*wc1.y + zg[6]*wc1.z + zg[7]*wc1.w;
    float saq = ao + qo;
    float sg[8];
    GATHER8(sg, saq);
    float at = cb[e] + sg[0]*wc0.x + sg[1]*wc0.y + sg[2]*wc0.z + sg[3]*wc0.w
                     + sg[4]*wc1.x + sg[5]*wc1.y + sg[6]*wc1.z + sg[7]*wc1.w;

    // ---- LayerNorm1 over e (xor butterflies within 8-group) ----
    float r1 = xo + at;
    float sm = r1;
    sm += SWZX(sm, 1); sm += SWZX(sm, 2); sm += SWZX(sm, 4);
    float mean = sm * 0.125f;
    float dv = r1 - mean;
    float vq = dv * dv;
    vq += SWZX(vq, 1); vq += SWZX(vq, 2); vq += SWZX(vq, 4);
    float rs = __builtin_amdgcn_rsqf(vq * 0.125f + 1e-5f);
    float hh = fmaf(dv * rs, g1[e], b1[e]);

    // ---- publish hh and zf = cos(hh + rxf) ----
    lds_hh[tblk][e] = hh;
    lds_zf[tblk][e] = __cosf(hh + rxf[e]);
    __syncthreads();

    // ---- FFN: 16x16 MFMA tile over the block's 16 tokens, split-K by wave ----
    const int m  = l & 15;            // token within tile
    const int kg = (l >> 4) * 4;      // k-group 0,4,8,12
    const half4 zh = {(__fp16)0.f, (__fp16)0.f, (__fp16)0.f, (__fp16)0.f};
    half4 bz = zh;
    if (l < 32) {
        float4 z4 = *reinterpret_cast<const float4*>(&lds_zf[m][kg]);
        half2v c0 = __builtin_amdgcn_cvt_pkrtz(z4.x, z4.y);
        half2v c1 = __builtin_amdgcn_cvt_pkrtz(z4.z, z4.w);
        bz.x = c0.x; bz.y = c0.y; bz.z = c1.x; bz.w = c1.y;
    } else if (l < 48) {
        bz.x = (__fp16)1.f;           // bias row k==8
    }

    const float4v zero4 = {0.f, 0.f, 0.f, 0.f};
    float4v acc = zero4;
    const int nf0 = wv * 16;
    #pragma unroll
    for (int i = 0; i < 16; ++i) {
        const int nf = nf0 + i;
        half4 a1f = a1ws[nf * 64 + l];
        half4 a2f = a2ws[nf * 64 + l];
        float4v d1 = __builtin_amdgcn_mfma_f32_16x16x16f16(a1f, bz, zero4, 0, 0, 0);
        d1.x = fmaxf(d1.x, 0.f); d1.y = fmaxf(d1.y, 0.f);
        d1.z = fmaxf(d1.z, 0.f); d1.w = fmaxf(d1.w, 0.f);
        half2v q0 = __builtin_amdgcn_cvt_pkrtz(d1.x, d1.y);
        half2v q1 = __builtin_amdgcn_cvt_pkrtz(d1.z, d1.w);
        half4 bu; bu.x = q0.x; bu.y = q0.y; bu.z = q1.x; bu.w = q1.y;
        acc = __builtin_amdgcn_mfma_f32_16x16x16f16(a2f, bu, acc, 0, 0, 0);
    }

    // ---- merge split-K partials (wave1 -> LDS), then wave0 epilogue ----
    if (wv == 1 && l < 32) {
        lds_acc[l][0] = acc.x; lds_acc[l][1] = acc.y;
        lds_acc[l][2] = acc.z; lds_acc[l][3] = acc.w;
    }
    __syncthreads();

    if (wv == 0 && l < 32) {
        float fo[4];
        fo[0] = acc.x + lds_acc[l][0]; fo[1] = acc.y + lds_acc[l][1];
        fo[2] = acc.z + lds_acc[l][2]; fo[3] = acc.w + lds_acc[l][3];

        float4 h4  = *reinterpret_cast<const float4*>(&lds_hh[m][kg]);
        float4 lb4 = *reinterpret_cast<const float4*>(l2b + kg);
        float r2[4];
        r2[0] = h4.x + fo[0] + lb4.x; r2[1] = h4.y + fo[1] + lb4.y;
        r2[2] = h4.z + fo[2] + lb4.z; r2[3] = h4.w + fo[3] + lb4.w;

        float part = ((r2[0] + r2[1]) + (r2[2] + r2[3]));
        float tot  = part + SWZX(part, 16);          // lanes l and l^16 pair
        float mean2 = tot * 0.125f;
        float d0 = r2[0] - mean2, d1_ = r2[1] - mean2,
              d2 = r2[2] - mean2, d3 = r2[3] - mean2;
        float vp = ((d0*d0 + d1_*d1_) + (d2*d2 + d3*d3));
        float vt = vp + SWZX(vp, 16);
        float rs2 = __builtin_amdgcn_rsqf(vt * 0.125f + 1e-5f);

        float4 g4 = *reinterpret_cast<const float4*>(g2 + kg);
        float4 bb = *reinterpret_cast<const float4*>(b2 + kg);
        float4 o;
        o.x = fmaf(d0 * rs2, g4.x, bb.x);
        o.y = fmaf(d1_ * rs2, g4.y, bb.y);
        o.z = fmaf(d2 * rs2, g4.z, bb.z);
        o.w = fmaf(d3 * rs2, g4.w, bb.w);

        float4* po = reinterpret_cast<float4*>(out + (blockIdx.x * 16 + m) * 8 + kg);
        *po = o;
    }
}

extern "C" void kernel_launch(void* const* d_in, const int* in_sizes, int n_in,
                              void* d_out, int out_size, void* d_ws, size_t ws_size,
                              hipStream_t stream) {
    const float* x   = (const float*)d_in[0];
    const float* ipw = (const float*)d_in[1];
    const float* ipb = (const float*)d_in[2];
    const float* opw = (const float*)d_in[3];
    const float* opb = (const float*)d_in[4];
    const float* rxa = (const float*)d_in[5];
    const float* cw  = (const float*)d_in[6];
    const float* cb  = (const float*)d_in[7];
    const float* g1  = (const float*)d_in[8];
    const float* b1  = (const float*)d_in[9];
    const float* rxf = (const float*)d_in[10];
    const float* l1w = (const float*)d_in[11];
    const float* l1b = (const float*)d_in[12];
    const float* l2w = (const float*)d_in[13];
    const float* l2b = (const float*)d_in[14];
    const float* g2  = (const float*)d_in[15];
    const float* b2  = (const float*)d_in[16];
    float* out = (float*)d_out;

    half4* a1ws = (half4*)d_ws;                    // 32 chunks * 64 lanes * 8B = 16KB
    half4* a2ws = (half4*)((char*)d_ws + 16384);   // 16KB

    pack_frags<<<dim3(16), dim3(256), 0, stream>>>(l1w, l1b, l2w, a1ws, a2ws);

    const int tokens = 16384 * 8;                  // 131072
    const int blocks = tokens / 16;                // 8192 blocks, 16 tokens each
    tbq_fused<<<dim3(blocks), dim3(128), 0, stream>>>(
        x, ipw, ipb, opw, opb, rxa, cw, cb, g1, b1, rxf,
        a1ws, a2ws, l2b, g2, b2, out);
}

// Round 11
// 29.682 us; speedup vs baseline: 1.1546x; 1.1546x over previous
//
#include <hip/hip_runtime.h>

// TransformerBlockQuantum: B=16384, S=8, E=8, H=8 (dk=1), NW=8, FFN=512.
// R11 = R10 with (a) DOT4 macro param rename (».w« collision), (b) lds_hh
// stride 12 (16B-aligned float4 reads).
// 2 lanes per token. lane l: p=l&1 (owns embeds/heads 4p..4p+3), t=l>>1.
// 4096 blocks x 1 wave -> 4 waves/SIMD (launch_bounds(64,4), <=128 VGPR).
// Front: per-lane 4 rows; partner exchange via xor-1 swizzle; attention
// j-gather via parity-preserving swizzle (j<<6)|0x11; ring lane-local.
// FFN: 2 16x16 MFMA tiles/wave, fragments streamed from d_ws (L2-hot),
// shared per iteration (2-chain ILP). Epilogue LN2 on lanes 0-31.

typedef __fp16 half2v __attribute__((ext_vector_type(2)));
typedef __fp16 half4  __attribute__((ext_vector_type(4)));
typedef float  float4v __attribute__((ext_vector_type(4)));

// partner exchange: id5 ^ 1
#define SWZ1(v) __int_as_float(__builtin_amdgcn_ds_swizzle(__float_as_int(v), (1 << 10) | 0x1F))
// epilogue pair: id5 ^ 16
#define SWZ16(v) __int_as_float(__builtin_amdgcn_ds_swizzle(__float_as_int(v), (16 << 10) | 0x1F))
// j-gather: new_id5 = (id5 & 0b10001) | (j<<1) -> same parity, same batch, token j
#define SWZJ_(v, jlit) __int_as_float(__builtin_amdgcn_ds_swizzle(__float_as_int(v), ((jlit) << 6) | 0x11))
#define GATHERJ(dst, src)                                   \
    do {                                                    \
        dst[0] = SWZJ_(src, 0); dst[1] = SWZJ_(src, 1);     \
        dst[2] = SWZJ_(src, 2); dst[3] = SWZJ_(src, 3);     \
        dst[4] = SWZJ_(src, 4); dst[5] = SWZJ_(src, 5);     \
        dst[6] = SWZJ_(src, 6); dst[7] = SWZJ_(src, 7);     \
    } while (0)

#define DOT4(a, vw) (fmaf((a)[3], (vw).w, fmaf((a)[2], (vw).z, fmaf((a)[1], (vw).y, (a)[0] * (vw).x))))

__global__ __launch_bounds__(256) void pack_frags(
    const float* __restrict__ l1w, const float* __restrict__ l1b,
    const float* __restrict__ l2w,
    half4* __restrict__ a1ws, half4* __restrict__ a2ws)
{
    int t = blockIdx.x * 256 + threadIdx.x;   // 0..4095
    int u = t & 2047;
    int nf = u >> 6, l = u & 63;
    int m = l & 15, k0 = (l >> 4) * 4;
    half4 r;
    if (t < 2048) {
        int f = nf * 16 + m;
        #pragma unroll
        for (int j = 0; j < 4; ++j) {
            int k = k0 + j;
            float v = (k < 8) ? l1w[f * 8 + k] : ((k == 8) ? l1b[f] : 0.f);
            r[j] = (__fp16)v;
        }
        a1ws[nf * 64 + l] = r;
    } else {
        #pragma unroll
        for (int j = 0; j < 4; ++j) {
            int k = k0 + j;
            float v = (m < 8) ? l2w[m * 512 + nf * 16 + k] : 0.f;
            r[j] = (__fp16)v;
        }
        a2ws[nf * 64 + l] = r;
    }
}

__global__ __launch_bounds__(64, 4) void tbq_fused(
    const float* __restrict__ x,
    const float* __restrict__ ipw, const float* __restrict__ ipb,
    const float* __restrict__ opw, const float* __restrict__ opb,
    const float* __restrict__ rxa,
    const float* __restrict__ cw,  const float* __restrict__ cb,
    const float* __restrict__ g1,  const float* __restrict__ b1,
    const float* __restrict__ rxf,
    const half4* __restrict__ a1ws, const half4* __restrict__ a2ws,
    const float* __restrict__ l2b,
    const float* __restrict__ g2,  const float* __restrict__ b2,
    float* __restrict__ out)
{
    __shared__ half4 lds_zf[32][2];          // [token][half] zf as half4
    __shared__ __align__(16) float lds_hh[32][12];   // stride 12 -> aligned f4

    const int l   = threadIdx.x;
    const int p   = l & 1;                   // embed/head half
    const int t   = l >> 1;                  // token in wave (0..31)
    const int e0  = p * 4;                   // first owned row index
    const int tok = blockIdx.x * 32 + t;
    const int base = tok * 8;
    const bool sel = (p == 0);

    // ---- x: own half + partner half ----
    float4 xo4 = *reinterpret_cast<const float4*>(x + base + e0);
    float xown[4] = {xo4.x, xo4.y, xo4.z, xo4.w};
    float xoth[4] = {SWZ1(xown[0]), SWZ1(xown[1]), SWZ1(xown[2]), SWZ1(xown[3])};
    float xlo[4], xhi[4];
    #pragma unroll
    for (int j = 0; j < 4; ++j) {
        xlo[j] = sel ? xown[j] : xoth[j];
        xhi[j] = sel ? xoth[j] : xown[j];
    }

    // ---- in_proj: own 4 rows of q, k, v ----
    const float4* ipw4 = reinterpret_cast<const float4*>(ipw);
    float q4[4], k4[4], v4[4];
    #pragma unroll
    for (int i = 0; i < 4; ++i) {
        int rq = e0 + i, rk = 8 + e0 + i, rv = 16 + e0 + i;
        float4 wl, wh;
        wl = ipw4[rq * 2]; wh = ipw4[rq * 2 + 1];
        q4[i] = ipb[rq] + DOT4(xlo, wl) + DOT4(xhi, wh);
        wl = ipw4[rk * 2]; wh = ipw4[rk * 2 + 1];
        k4[i] = ipb[rk] + DOT4(xlo, wl) + DOT4(xhi, wh);
        wl = ipw4[rv * 2]; wh = ipw4[rv * 2 + 1];
        v4[i] = ipb[rv] + DOT4(xlo, wl) + DOT4(xhi, wh);
    }

    // ---- attention: 4 owned heads, j-gather k/v across own batch ----
    float or4[4];
    #pragma unroll
    for (int i = 0; i < 4; ++i) {
        float kk[8], vg[8];
        GATHERJ(kk, k4[i]);
        GATHERJ(vg, v4[i]);
        const float qh = q4[i];
        float sc[8];
        #pragma unroll
        for (int j = 0; j < 8; ++j) sc[j] = qh * kk[j];
        float mx = fmaxf(fmaxf(fmaxf(sc[0], sc[1]), fmaxf(sc[2], sc[3])),
                         fmaxf(fmaxf(sc[4], sc[5]), fmaxf(sc[6], sc[7])));
        float pe[8];
        #pragma unroll
        for (int j = 0; j < 8; ++j) pe[j] = __expf(sc[j] - mx);
        float sum = ((pe[0] + pe[1]) + (pe[2] + pe[3])) + ((pe[4] + pe[5]) + (pe[6] + pe[7]));
        float ov = 0.f;
        #pragma unroll
        for (int j = 0; j < 8; ++j) ov = fmaf(pe[j], vg[j], ov);
        or4[i] = ov * __builtin_amdgcn_rcpf(sum);
    }

    // ---- out_proj: own 4 rows; orow full via partner exchange ----
    float ooth[4] = {SWZ1(or4[0]), SWZ1(or4[1]), SWZ1(or4[2]), SWZ1(or4[3])};
    float olo[4], ohi[4];
    #pragma unroll
    for (int j = 0; j < 4; ++j) {
        olo[j] = sel ? or4[j] : ooth[j];
        ohi[j] = sel ? ooth[j] : or4[j];
    }
    const float4* opw4 = reinterpret_cast<const float4*>(opw);
    float ao4[4];
    #pragma unroll
    for (int i = 0; i < 4; ++i) {
        int r = e0 + i;
        float4 wl = opw4[r * 2], wh = opw4[r * 2 + 1];
        ao4[i] = opb[r] + DOT4(olo, wl) + DOT4(ohi, wh);
    }

    // ---- quantum ring: full c row locally, full z locally ----
    float c4[4];
    #pragma unroll
    for (int i = 0; i < 4; ++i) c4[i] = __cosf(ao4[i] + rxa[e0 + i]);
    float coth[4] = {SWZ1(c4[0]), SWZ1(c4[1]), SWZ1(c4[2]), SWZ1(c4[3])};
    float cc[8];
    #pragma unroll
    for (int j = 0; j < 4; ++j) {
        cc[j]     = sel ? c4[j] : coth[j];
        cc[4 + j] = sel ? coth[j] : c4[j];
    }
    float z8[8];
    {
        float run = cc[0];
        #pragma unroll
        for (int w = 1; w < 8; ++w) { run *= cc[w]; z8[w] = run; }
        float s17 = cc[1];
        #pragma unroll
        for (int w = 2; w < 8; ++w) s17 *= cc[w];
        z8[0] = s17;
    }

    // ---- combine1 (z8 full per-lane: no exchange) ----
    const float4* cw4 = reinterpret_cast<const float4*>(cw);
    float zlo[4] = {z8[0], z8[1], z8[2], z8[3]};
    float zhi[4] = {z8[4], z8[5], z8[6], z8[7]};
    float sa4[4];
    #pragma unroll
    for (int i = 0; i < 4; ++i) {
        int r = e0 + i;
        float4 wl = cw4[r * 2], wh = cw4[r * 2 + 1];
        sa4[i] = ao4[i] + cb[r] + DOT4(zlo, wl) + DOT4(zhi, wh);
    }
    // ---- combine2 (saq needs partner half) ----
    float soth[4] = {SWZ1(sa4[0]), SWZ1(sa4[1]), SWZ1(sa4[2]), SWZ1(sa4[3])};
    float slo[4], shi[4];
    #pragma unroll
    for (int j = 0; j < 4; ++j) {
        slo[j] = sel ? sa4[j] : soth[j];
        shi[j] = sel ? soth[j] : sa4[j];
    }
    float at4[4];
    #pragma unroll
    for (int i = 0; i < 4; ++i) {
        int r = e0 + i;
        float4 wl = cw4[r * 2], wh = cw4[r * 2 + 1];
        at4[i] = cb[r] + DOT4(slo, wl) + DOT4(shi, wh);
    }

    // ---- LayerNorm1 over 8 (own 4 + partner via xor-1) ----
    float r1[4];
    #pragma unroll
    for (int i = 0; i < 4; ++i) r1[i] = xown[i] + at4[i];
    float s4 = ((r1[0] + r1[1]) + (r1[2] + r1[3]));
    float mean = (s4 + SWZ1(s4)) * 0.125f;
    float dv[4];
    float vq = 0.f;
    #pragma unroll
    for (int i = 0; i < 4; ++i) { dv[i] = r1[i] - mean; vq = fmaf(dv[i], dv[i], vq); }
    float var = (vq + SWZ1(vq)) * 0.125f;
    float rs = __builtin_amdgcn_rsqf(var + 1e-5f);
    float hh4[4];
    #pragma unroll
    for (int i = 0; i < 4; ++i) hh4[i] = fmaf(dv[i] * rs, g1[e0 + i], b1[e0 + i]);

    // ---- publish hh (f32x4) and zf (half4) ----
    *reinterpret_cast<float4*>(&lds_hh[t][e0]) =
        make_float4(hh4[0], hh4[1], hh4[2], hh4[3]);
    {
        float zf0 = __cosf(hh4[0] + rxf[e0]);
        float zf1 = __cosf(hh4[1] + rxf[e0 + 1]);
        float zf2 = __cosf(hh4[2] + rxf[e0 + 2]);
        float zf3 = __cosf(hh4[3] + rxf[e0 + 3]);
        half2v c0 = __builtin_amdgcn_cvt_pkrtz(zf0, zf1);
        half2v c1 = __builtin_amdgcn_cvt_pkrtz(zf2, zf3);
        half4 zp; zp.x = c0.x; zp.y = c0.y; zp.z = c1.x; zp.w = c1.y;
        lds_zf[t][p] = zp;
    }
    __syncthreads();

    // ---- FFN: 2 tiles (tokens 0-15, 16-31), fragments streamed from d_ws ----
    const int m  = l & 15;
    const half4 zh = {(__fp16)0.f, (__fp16)0.f, (__fp16)0.f, (__fp16)0.f};
    half4 bz0 = zh, bz1 = zh;
    if (l < 32) {
        bz0 = lds_zf[m][l >> 4];
        bz1 = lds_zf[16 + m][l >> 4];
    } else if (l < 48) {
        bz0.x = (__fp16)1.f; bz1.x = (__fp16)1.f;   // bias row k==8
    }

    const float4v zero4 = {0.f, 0.f, 0.f, 0.f};
    float4v acc0 = zero4, acc1 = zero4;
    #pragma unroll
    for (int nf = 0; nf < 32; ++nf) {
        half4 a1f = a1ws[nf * 64 + l];
        half4 a2f = a2ws[nf * 64 + l];
        float4v d0 = __builtin_amdgcn_mfma_f32_16x16x16f16(a1f, bz0, zero4, 0, 0, 0);
        float4v d1 = __builtin_amdgcn_mfma_f32_16x16x16f16(a1f, bz1, zero4, 0, 0, 0);
        d0.x = fmaxf(d0.x, 0.f); d0.y = fmaxf(d0.y, 0.f);
        d0.z = fmaxf(d0.z, 0.f); d0.w = fmaxf(d0.w, 0.f);
        d1.x = fmaxf(d1.x, 0.f); d1.y = fmaxf(d1.y, 0.f);
        d1.z = fmaxf(d1.z, 0.f); d1.w = fmaxf(d1.w, 0.f);
        half2v q00 = __builtin_amdgcn_cvt_pkrtz(d0.x, d0.y);
        half2v q01 = __builtin_amdgcn_cvt_pkrtz(d0.z, d0.w);
        half2v q10 = __builtin_amdgcn_cvt_pkrtz(d1.x, d1.y);
        half2v q11 = __builtin_amdgcn_cvt_pkrtz(d1.z, d1.w);
        half4 bu0; bu0.x = q00.x; bu0.y = q00.y; bu0.z = q01.x; bu0.w = q01.y;
        half4 bu1; bu1.x = q10.x; bu1.y = q10.y; bu1.z = q11.x; bu1.w = q11.y;
        acc0 = __builtin_amdgcn_mfma_f32_16x16x16f16(a2f, bu0, acc0, 0, 0, 0);
        acc1 = __builtin_amdgcn_mfma_f32_16x16x16f16(a2f, bu1, acc1, 0, 0, 0);
    }

    // ---- epilogue: residual + LN2 + store, lanes 0-31, both tiles ----
    if (l < 32) {
        const int kg4 = (l >> 4) * 4;
        float4 lb4 = *reinterpret_cast<const float4*>(l2b + kg4);
        float4 g4  = *reinterpret_cast<const float4*>(g2 + kg4);
        float4 bb4 = *reinterpret_cast<const float4*>(b2 + kg4);

        #pragma unroll
        for (int tt = 0; tt < 2; ++tt) {
            float4v acc = tt ? acc1 : acc0;
            float4 h4 = *reinterpret_cast<const float4*>(&lds_hh[tt * 16 + m][kg4]);
            float r2[4];
            r2[0] = h4.x + acc.x + lb4.x;
            r2[1] = h4.y + acc.y + lb4.y;
            r2[2] = h4.z + acc.z + lb4.z;
            r2[3] = h4.w + acc.w + lb4.w;
            float part = ((r2[0] + r2[1]) + (r2[2] + r2[3]));
            float mean2 = (part + SWZ16(part)) * 0.125f;
            float d0 = r2[0] - mean2, d1_ = r2[1] - mean2,
                  d2 = r2[2] - mean2, d3 = r2[3] - mean2;
            float vp = ((d0 * d0 + d1_ * d1_) + (d2 * d2 + d3 * d3));
            float rs2 = __builtin_amdgcn_rsqf((vp + SWZ16(vp)) * 0.125f + 1e-5f);
            float4 o;
            o.x = fmaf(d0 * rs2, g4.x, bb4.x);
            o.y = fmaf(d1_ * rs2, g4.y, bb4.y);
            o.z = fmaf(d2 * rs2, g4.z, bb4.z);
            o.w = fmaf(d3 * rs2, g4.w, bb4.w);
            *reinterpret_cast<float4*>(out + (blockIdx.x * 32 + tt * 16 + m) * 8 + kg4) = o;
        }
    }
}

extern "C" void kernel_launch(void* const* d_in, const int* in_sizes, int n_in,
                              void* d_out, int out_size, void* d_ws, size_t ws_size,
                              hipStream_t stream) {
    const float* x   = (const float*)d_in[0];
    const float* ipw = (const float*)d_in[1];
    const float* ipb = (const float*)d_in[2];
    const float* opw = (const float*)d_in[3];
    const float* opb = (const float*)d_in[4];
    const float* rxa = (const float*)d_in[5];
    const float* cw  = (const float*)d_in[6];
    const float* cb  = (const float*)d_in[7];
    const float* g1  = (const float*)d_in[8];
    const float* b1  = (const float*)d_in[9];
    const float* rxf = (const float*)d_in[10];
    const float* l1w = (const float*)d_in[11];
    const float* l1b = (const float*)d_in[12];
    const float* l2w = (const float*)d_in[13];
    const float* l2b = (const float*)d_in[14];
    const float* g2  = (const float*)d_in[15];
    const float* b2  = (const float*)d_in[16];
    float* out = (float*)d_out;

    half4* a1ws = (half4*)d_ws;                    // 16KB
    half4* a2ws = (half4*)((char*)d_ws + 16384);   // 16KB

    pack_frags<<<dim3(16), dim3(256), 0, stream>>>(l1w, l1b, l2w, a1ws, a2ws);

    const int tokens = 16384 * 8;                  // 131072
    const int blocks = tokens / 32;                // 4096 blocks, 32 tokens each
    tbq_fused<<<dim3(blocks), dim3(64), 0, stream>>>(
        x, ipw, ipb, opw, opb, rxa, cw, cb, g1, b1, rxf,
        a1ws, a2ws, l2b, g2, b2, out);
}